// Round 2
// baseline (102.725 us; speedup 1.0000x reference)
//
#include <hip/hip_runtime.h>
#include <hip/hip_bf16.h>

// Euler characteristic curve (ECC) of V-construction cubical complex.
// x: [64,3,224,224] fp32 in [0,1). Out: [64, 96] fp32 = per-(b,c) ECC over
// tseq = linspace(0,1,32). Flattened out index = img*32 + t  (img = b*3+c).
//
// Per pixel (i,j): cells with top-left corner at (i,j):
//   vertex  f = x[i][j]                                  sign +1
//   h-edge  f = max(x[i][j], x[i][j+1])     (j<W-1)      sign -1
//   v-edge  f = max(x[i][j], x[i+1][j])     (i<H-1)      sign -1
//   square  f = max of 2x2                  (both)       sign +1
// bin idx = first t with tseq[t] >= f  ==  ceil(31*f) for f in [0,1).
//
// R2: per-thread int32 LDS histograms updated with atomicAdd -> fire-and-forget
// ds_add_u32 (1 DS op/increment, no read-modify-write dependency chain; R1's
// short RMW serialized on potential aliasing between the 4 per-pixel bins).

#define H 224
#define W 224
#define STEPS 32
#define BANDS 8
#define ROWS_PER_BLOCK (H / BANDS)   // 28
#define NTHR 256

__device__ __forceinline__ int bin_of(float f) {
    int i = (int)ceilf(f * 31.0f);   // f in [0,1) => i in [0,31]
    return i > 31 ? 31 : i;          // defensive only
}

__global__ __launch_bounds__(NTHR) void ecc_hist_kernel(
        const float* __restrict__ x, int* __restrict__ ghist)
{
    // Per-thread privatized i32 histograms, bin-major: lh[bin*NTHR + tid].
    // Bank = tid%32 for every update -> 2-way aliasing across the wave = free.
    __shared__ int lh[STEPS * NTHR];     // 32 KB -> 4 blocks/CU

    const int tid = threadIdx.x;
    #pragma unroll
    for (int b = 0; b < STEPS; ++b) lh[b * NTHR + tid] = 0;
    __syncthreads();

    const int band = blockIdx.x & (BANDS - 1);
    const int img  = blockIdx.x / BANDS;          // 0..191
    const float* __restrict__ p = x + (size_t)img * (H * W);
    const int r0 = band * ROWS_PER_BLOCK;

    const int j = tid;
    int* __restrict__ lhp = lh + tid;

    if (j < W) {
        const bool hasR = (j < W - 1);
        float cur  = p[r0 * W + j];
        float curR = hasR ? p[r0 * W + j + 1] : 0.0f;
        #pragma unroll 7
        for (int r = r0; r < r0 + ROWS_PER_BLOCK; ++r) {
            const bool hasD = (r < H - 1);
            float dn  = hasD ? p[(r + 1) * W + j] : 0.0f;
            float dnR = (hasD && hasR) ? p[(r + 1) * W + j + 1] : 0.0f;

            atomicAdd(&lhp[bin_of(cur) * NTHR], 1);                       // vertex +1
            if (hasR)
                atomicAdd(&lhp[bin_of(fmaxf(cur, curR)) * NTHR], -1);     // h-edge -1
            if (hasD) {
                atomicAdd(&lhp[bin_of(fmaxf(cur, dn)) * NTHR], -1);       // v-edge -1
                if (hasR) {
                    float m = fmaxf(fmaxf(cur, curR), fmaxf(dn, dnR));
                    atomicAdd(&lhp[bin_of(m) * NTHR], 1);                 // square +1
                }
            }
            cur = dn; curR = dnR;
        }
    }
    __syncthreads();

    // Reduce 256 thread-hists -> 32 bins. thread = g*32 + b, g in [0,8):
    // each thread sums 32 consecutive ints of bin b via int4 LDS reads,
    // then one global atomic per thread (8 partials per (img,bin)).
    const int b = tid & 31;
    const int g = tid >> 5;
    const int4* __restrict__ row = (const int4*)(lh + b * NTHR + g * 32);
    int sum = 0;
    #pragma unroll
    for (int k = 0; k < 8; ++k) {
        int4 v = row[k];
        sum += v.x + v.y + v.z + v.w;
    }
    atomicAdd(&ghist[img * STEPS + b], sum);
}

__global__ void ecc_cumsum_kernel(const int* __restrict__ ghist,
                                  float* __restrict__ out, int nimg)
{
    int img = blockIdx.x * blockDim.x + threadIdx.x;
    if (img < nimg) {
        int s = 0;
        #pragma unroll
        for (int t = 0; t < STEPS; ++t) {
            s += ghist[img * STEPS + t];
            out[img * STEPS + t] = (float)s;
        }
    }
}

extern "C" void kernel_launch(void* const* d_in, const int* in_sizes, int n_in,
                              void* d_out, int out_size, void* d_ws, size_t ws_size,
                              hipStream_t stream) {
    const float* x = (const float*)d_in[0];
    float* out = (float*)d_out;
    int* ghist = (int*)d_ws;

    const int nimg = in_sizes[0] / (H * W);      // 192

    hipMemsetAsync(ghist, 0, (size_t)nimg * STEPS * sizeof(int), stream);

    dim3 grid1(nimg * BANDS);
    ecc_hist_kernel<<<grid1, NTHR, 0, stream>>>(x, ghist);

    int thr2 = 256;
    int blk2 = (nimg + thr2 - 1) / thr2;
    ecc_cumsum_kernel<<<blk2, thr2, 0, stream>>>(ghist, out, nimg);
}

// Round 3
// 80.720 us; speedup vs baseline: 1.2726x; 1.2726x over previous
//
#include <hip/hip_runtime.h>
#include <hip/hip_bf16.h>

// Euler characteristic curve (ECC) of V-construction cubical complex.
// x: [64,3,224,224] fp32 in [0,1). Out: [64,96] fp32 = per-(b,c) ECC over
// tseq = linspace(0,1,32); out[img*32+t], img = b*3+c.
//
// Cell->bin: bin(f) = ceil(31*f) (searchsorted-left on linspace(0,1,32)).
// bin is monotonic, so bin(max(a,b)) = max(bin(a),bin(b)): work entirely in
// int bin domain. Per pixel, the 4 cells collapse into two signed pairs:
//   pair1 (vertex +1 @ b00, h-edge -1 @ max(b00,b01)):
//       fires iff b01 > b00:  +1@b00, -1@b01        (else exact cancel)
//   pair2 (v-edge -1 @ L=max(b00,b10), square +1 @ max(L, max(b01,b11))):
//       with M_k = max(B_k, C_k): fires iff M_{k+1} > M_k: -1@M_k, +1@M_{k+1}
// Boundaries are branch-free via sentinel bins: missing-right -> 33,
// missing-below -> 32; spurious +-1 land in garbage bins 32/33 (discarded).
//
// R3: 4 waves share one 34x64 int hist (8.7 KB LDS vs 32 KB -> ~24 waves/CU),
// float4 row loads (VMEM instrs /4), predicated pair atomics (~2 active
// lanes/pixel). Attacks R2's latency-bound profile (VALUBusy 16%, occ 29%).

#define H 224
#define W 224
#define STEPS 32
#define NBINS 34            // 32 real + garbage bins 32 (no-below), 33 (no-right)
#define NCOL 64
#define BANDS 8
#define BAND_ROWS 28        // per block
#define SUB_ROWS 7          // per wave (4 waves per block)
#define NTHR 256

__device__ __forceinline__ int bin_of(float f) {
    int i = (int)ceilf(f * 31.0f);   // f in [0,1) -> [0,31]
    return i > 31 ? 31 : i;          // defensive clamp
}

__global__ __launch_bounds__(NTHR, 4) void ecc_hist_kernel(
        const float* __restrict__ x, int* __restrict__ ghist)
{
    // Shared across the block's 4 waves. Update addr = (bin*64 + c)*4:
    // bank = c%32 -> 2-way wave aliasing (free, m136).
    __shared__ int lh[NBINS * NCOL];     // 8704 B
    __shared__ int partial[NTHR];        // 1 KB

    const int tid = threadIdx.x;
    #pragma unroll
    for (int i = tid; i < NBINS * NCOL; i += NTHR) lh[i] = 0;
    __syncthreads();

    const int band = blockIdx.x & (BANDS - 1);
    const int img  = blockIdx.x / BANDS;          // 0..191
    const float* __restrict__ p = x + (size_t)img * (H * W);

    const int c = tid & 63;      // column group: cols 4c..4c+3 (active c<56)
    const int s = tid >> 6;      // sub-band id == wave id (rows uniform per wave)

    if (c < 56) {
        const int  j0    = c << 2;
        const bool lastc = (c == 55);
        const int  jn    = lastc ? (W - 1) : (j0 + 4);  // clamped (value unused when lastc)
        const int  r0    = band * BAND_ROWS + s * SUB_ROWS;
        int* __restrict__ lhc = lh + c;

        float4 F = *(const float4*)(p + r0 * W + j0);
        float  fn = p[r0 * W + jn];
        int B0 = bin_of(F.x), B1 = bin_of(F.y), B2 = bin_of(F.z), B3 = bin_of(F.w);
        int Bn = lastc ? 33 : bin_of(fn);

        for (int r = r0; r < r0 + SUB_ROWS; ++r) {
            int C0, C1, C2, C3, Cn;
            if (r < H - 1) {                      // wave-uniform branch
                float4 G = *(const float4*)(p + (r + 1) * W + j0);
                float  gn = p[(r + 1) * W + jn];
                C0 = bin_of(G.x); C1 = bin_of(G.y); C2 = bin_of(G.z); C3 = bin_of(G.w);
                Cn = lastc ? 33 : bin_of(gn);
            } else {
                C0 = C1 = C2 = C3 = 32; Cn = 32;  // kill pair2 on bottom row
            }

            // pair1: vertex/h-edge run boundaries along the B row
            if (B1 > B0) { atomicAdd(&lhc[B0 << 6],  1); atomicAdd(&lhc[B1 << 6], -1); }
            if (B2 > B1) { atomicAdd(&lhc[B1 << 6],  1); atomicAdd(&lhc[B2 << 6], -1); }
            if (B3 > B2) { atomicAdd(&lhc[B2 << 6],  1); atomicAdd(&lhc[B3 << 6], -1); }
            if (Bn > B3) { atomicAdd(&lhc[B3 << 6],  1); atomicAdd(&lhc[Bn << 6], -1); }

            // pair2: v-edge/square run boundaries along M_k = max(B_k, C_k)
            {
                int M0 = max(B0, C0), M1 = max(B1, C1), M2 = max(B2, C2),
                    M3 = max(B3, C3), Mn = max(Bn, Cn);
                if (M1 > M0) { atomicAdd(&lhc[M0 << 6], -1); atomicAdd(&lhc[M1 << 6], 1); }
                if (M2 > M1) { atomicAdd(&lhc[M1 << 6], -1); atomicAdd(&lhc[M2 << 6], 1); }
                if (M3 > M2) { atomicAdd(&lhc[M2 << 6], -1); atomicAdd(&lhc[M3 << 6], 1); }
                if (Mn > M3) { atomicAdd(&lhc[M3 << 6], -1); atomicAdd(&lhc[Mn << 6], 1); }
            }

            B0 = C0; B1 = C1; B2 = C2; B3 = C3; Bn = Cn;
        }
    }
    __syncthreads();

    // Reduce 64 columns -> 32 bins (garbage bins 32/33 dropped).
    const int b = tid >> 3;              // 0..31
    const int g = tid & 7;               // 8 col-groups of 8
    const int4* row = (const int4*)(lh + (b << 6) + (g << 3));
    int4 v0 = row[0], v1 = row[1];
    partial[tid] = v0.x + v0.y + v0.z + v0.w + v1.x + v1.y + v1.z + v1.w;
    __syncthreads();

    if (tid < 32) {
        const int4* pr = (const int4*)(partial + (tid << 3));
        int4 a0 = pr[0], a1 = pr[1];
        int s8 = a0.x + a0.y + a0.z + a0.w + a1.x + a1.y + a1.z + a1.w;
        atomicAdd(&ghist[img * STEPS + tid], s8);
    }
}

__global__ void ecc_cumsum_kernel(const int* __restrict__ ghist,
                                  float* __restrict__ out, int nimg)
{
    int img = blockIdx.x * blockDim.x + threadIdx.x;
    if (img < nimg) {
        int s = 0;
        #pragma unroll
        for (int t = 0; t < STEPS; ++t) {
            s += ghist[img * STEPS + t];
            out[img * STEPS + t] = (float)s;
        }
    }
}

extern "C" void kernel_launch(void* const* d_in, const int* in_sizes, int n_in,
                              void* d_out, int out_size, void* d_ws, size_t ws_size,
                              hipStream_t stream) {
    const float* x = (const float*)d_in[0];
    float* out = (float*)d_out;
    int* ghist = (int*)d_ws;

    const int nimg = in_sizes[0] / (H * W);      // 192

    hipMemsetAsync(ghist, 0, (size_t)nimg * STEPS * sizeof(int), stream);

    dim3 grid1(nimg * BANDS);
    ecc_hist_kernel<<<grid1, NTHR, 0, stream>>>(x, ghist);

    int thr2 = 256;
    int blk2 = (nimg + thr2 - 1) / thr2;
    ecc_cumsum_kernel<<<blk2, thr2, 0, stream>>>(ghist, out, nimg);
}